// Round 6
// baseline (127.713 us; speedup 1.0000x reference)
//
#include <hip/hip_runtime.h>
#include <hip/hip_bf16.h>
#include <math.h>

// Problem constants
#define BB 4
#define CC 64
#define HH 128
#define WW 128
#define HW 16384
#define CHW (CC*HW)

typedef __bf16 bf16;
typedef __attribute__((ext_vector_type(8))) __bf16 bf16x8;
typedef __attribute__((ext_vector_type(4))) __bf16 bf16x4;
typedef __attribute__((ext_vector_type(4))) float f32x4;
typedef __attribute__((ext_vector_type(4))) unsigned short u16x4;

#define MFMA(a, b, c) __builtin_amdgcn_mfma_f32_16x16x32_bf16((a), (b), (c), 0, 0, 0)

// ---- Pre-kernel: x NCHW -> NHWC bf16 (blocks 0..1023) + weight frags ----
__global__ __launch_bounds__(256) void k_pre(const float* __restrict__ x,
        bf16* __restrict__ xt,
        const float* __restrict__ dw, const float* __restrict__ ow,
        const float* __restrict__ mw,
        bf16* __restrict__ wfd_hi, bf16* __restrict__ wfd_lo,
        bf16* __restrict__ wfo_hi, bf16* __restrict__ wfo_lo) {
    __shared__ float tile[64][65];
    if (blockIdx.x < 1024) {
        int b    = blockIdx.x >> 8;
        int s0   = (blockIdx.x & 255) * 64;
        int t    = threadIdx.x;
        const float* xb = x + (size_t)b * CHW;
        // float4 reads: 1024 tasks = 64 rows x 16 col4-chunks
        #pragma unroll
        for (int it = 0; it < 4; ++it) {
            int task = it * 256 + t;
            int c    = task >> 4;
            int col4 = (task & 15) * 4;
            float4 v = *(const float4*)&xb[(size_t)c * HW + s0 + col4];
            tile[c][col4 + 0] = v.x;
            tile[c][col4 + 1] = v.y;
            tile[c][col4 + 2] = v.z;
            tile[c][col4 + 3] = v.w;
        }
        __syncthreads();
        bf16* xtb = xt + (size_t)b * CHW;
        #pragma unroll
        for (int it = 0; it < 2; ++it) {
            int task = it * 256 + t;                // 512 tasks: 64 s x 8 ch-chunks
            int s = task >> 3, ch0 = (task & 7) * 8;
            bf16x8 v;
            #pragma unroll
            for (int j = 0; j < 8; ++j) v[j] = (bf16)tile[ch0 + j][s];
            *(bf16x8*)&xtb[(size_t)(s0 + s) * 64 + ch0] = v;
        }
    } else {
        int idx = (blockIdx.x - 1024) * 256 + threadIdx.x;
        if (idx < 36864) {                          // deform frags: 4 nt * 18 ks * 64 lanes * 8
            int j    = idx & 7;
            int lane = (idx >> 3) & 63;
            int ks   = (idx >> 9) % 18;
            int nt   = idx / (512 * 18);
            int n    = nt * 16 + (lane & 15);
            int kglob = ks * 32 + (lane >> 4) * 8 + j;
            int kk = kglob >> 6, c = kglob & 63;    // K-order: k = kk*64 + c
            float w = dw[(n * 64 + c) * 9 + kk];
            bf16 h = (bf16)w;
            wfd_hi[idx] = h;
            wfd_lo[idx] = (bf16)(w - (float)h);
        } else {
            int idx2 = idx - 36864;                 // offmask frags: 2 nt
            int j    = idx2 & 7;
            int lane = (idx2 >> 3) & 63;
            int ks   = (idx2 >> 9) % 18;
            int nt   = idx2 / (512 * 18);
            int ch   = nt * 16 + (lane & 15);
            int kglob = ks * 32 + (lane >> 4) * 8 + j;
            int kk = kglob >> 6, c = kglob & 63;
            float w = 0.0f;
            if (ch < 18)      w = ow[(ch * 64 + c) * 9 + kk];
            else if (ch < 27) w = mw[((ch - 18) * 64 + c) * 9 + kk];
            bf16 h = (bf16)w;
            wfo_hi[idx2] = h;
            wfo_lo[idx2] = (bf16)(w - (float)h);
        }
    }
}

// ---- Fused kernel: 32 positions/block, 2048 blocks (6 blocks/CU by LDS) ----
// B : offset/mask GEMM. wave = (st2, ntile): each wave one 16-ch n-tile of one
//     st -> om_s directly (no reduce). 36 MFMA/wave.
// C1: 288 bilinear scalar tasks -> sampw/sampo (LDS)
// per st (2):
//   C2: thread (khalf,prow,c8): gather kk-half of row prow -> a_s (A-frag layout)
//   D : deform GEMM, wave = o-tile, hi-only
__global__ __launch_bounds__(256) void k_fused(const bf16* __restrict__ xt,
        const bf16* __restrict__ wfo_hi, const bf16* __restrict__ wfo_lo,
        const bf16* __restrict__ wfd_hi,
        const float* __restrict__ ob, const float* __restrict__ mb,
        const float* __restrict__ db, float* __restrict__ out) {
    __shared__ __align__(16) bf16 a_s[18 * 64 * 8];        // 18432 B
    __shared__ float om_s[27 * 32];                        // 3456 B
    __shared__ __align__(8) bf16 sampw[288 * 4];           // 2304 B
    __shared__ __align__(8) unsigned short sampo[288 * 4]; // 2304 B

    // XCD-chunked swizzle (2048 blocks, 8 XCDs, bijective)
    int bid = (blockIdx.x & 7) * 256 + (blockIdx.x >> 3);
    int pos0 = bid * 32;                            // row-aligned (128%32==0)
    int wo0 = pos0 & 127;
    int ho  = (pos0 >> 7) & 127;
    int b   = pos0 >> 14;
    int t = threadIdx.x, wave = t >> 6, lane = t & 63;
    int m = lane & 15, g = lane >> 4;
    const bf16* xtb = xt + (size_t)b * CHW;

    // ---- Phase B: wave = (st2, ntile) ----
    {
        int st2 = wave >> 1, ntile = wave & 1;
        f32x4 acc = {0.f, 0.f, 0.f, 0.f};
        const bf16x8* bh = (const bf16x8*)wfo_hi + ntile * 18 * 64 + lane;
        const bf16x8* bl = (const bf16x8*)wfo_lo + ntile * 18 * 64 + lane;
        #pragma unroll
        for (int kk = 0; kk < 9; ++kk) {
            int y  = ho + kk / 3 - 1;
            int xx = wo0 + st2 * 16 + m + (kk % 3) - 1;
            bf16x8 ae = {};
            bf16x8 ao = {};
            if ((unsigned)y < 128u && (unsigned)xx < 128u) {
                const bf16* bp = xtb + ((size_t)(y * 128 + xx) << 6);
                ae = *(const bf16x8*)(bp + g * 8);
                ao = *(const bf16x8*)(bp + 32 + g * 8);
            }
            int ks0 = 2 * kk, ks1 = 2 * kk + 1;
            acc = MFMA(ae, bh[ks0 * 64], acc);
            acc = MFMA(ae, bl[ks0 * 64], acc);
            acc = MFMA(ao, bh[ks1 * 64], acc);
            acc = MFMA(ao, bl[ks1 * 64], acc);
        }
        int ch = ntile * 16 + m;
        int p32 = st2 * 16 + g * 4;
        if (ch < 27) {
            float bias = (ch < 18) ? ob[ch] : mb[ch - 18];
            #pragma unroll
            for (int r = 0; r < 4; ++r) {
                float v = acc[r] + bias;
                if (ch >= 18) v = 1.0f / (1.0f + __expf(-v));
                om_s[ch * 32 + p32 + r] = v;
            }
        }
    }
    __syncthreads();

    // ---- Phase C1: bilinear scalar precompute (288 tasks) ----
    for (int task = t; task < 288; task += 256) {
        int p32 = task / 9, k = task - p32 * 9;
        float dy = om_s[(2 * k) * 32 + p32];
        float dx = om_s[(2 * k + 1) * 32 + p32];
        float mk = om_s[(18 + k) * 32 + p32];
        float py = (float)(ho - 1 + k / 3) + dy;
        float px = (float)(wo0 + p32 - 1 + (k % 3)) + dx;
        float y0f = floorf(py), x0f = floorf(px);
        float fy = py - y0f, fx = px - x0f;
        int y0 = (int)y0f, x0 = (int)x0f;
        int y1 = y0 + 1,  x1 = x0 + 1;
        bool vy0 = (unsigned)y0 < 128u, vy1 = (unsigned)y1 < 128u;
        bool vx0 = (unsigned)x0 < 128u, vx1 = (unsigned)x1 < 128u;
        int y0c = min(max(y0, 0), 127), y1c = min(max(y1, 0), 127);
        int x0c = min(max(x0, 0), 127), x1c = min(max(x1, 0), 127);
        bf16x4 wv;
        wv.x = (bf16)((vy0 && vx0) ? mk * (1.f - fy) * (1.f - fx) : 0.f);
        wv.y = (bf16)((vy0 && vx1) ? mk * (1.f - fy) * fx         : 0.f);
        wv.z = (bf16)((vy1 && vx0) ? mk * fy * (1.f - fx)         : 0.f);
        wv.w = (bf16)((vy1 && vx1) ? mk * fy * fx                 : 0.f);
        u16x4 ov;
        ov.x = (unsigned short)(y0c * 128 + x0c);
        ov.y = (unsigned short)(y0c * 128 + x1c);
        ov.z = (unsigned short)(y1c * 128 + x0c);
        ov.w = (unsigned short)(y1c * 128 + x1c);
        *(bf16x4*)&sampw[task * 4] = wv;
        *(u16x4*)&sampo[task * 4] = ov;
    }
    __syncthreads();

    // ---- st loop: C2 gather (kk-half split) -> D GEMM ----
    const bf16x8* bhd = (const bf16x8*)wfd_hi + (size_t)wave * 18 * 64 + lane;
    int fle = ((m ^ g) + (g << 4)) * 8;             // D-read offsets (elements)
    int flo = ((m ^ g ^ 4) + (g << 4)) * 8;
    int khalf = t >> 7;
    int prow  = (t >> 3) & 15;
    int c8    = (t & 7) * 8;
    int kpar  = c8 >> 5;
    int gch   = (c8 & 31) >> 3;
    int flw   = (prow ^ gch ^ (kpar << 2)) + (gch << 4);   // write slot (16B units)
    char* abw = (char*)a_s + (flw << 4);

    #pragma unroll
    for (int st = 0; st < 2; ++st) {
        int taskbase = (st * 16 + prow) * 9;
        auto gather1 = [&](int kk) {
            int task = taskbase + kk;
            bf16x4 wb = *(const bf16x4*)&sampw[task * 4];
            u16x4  o4 = *(const u16x4*)&sampo[task * 4];
            bf16x8 v00 = *(const bf16x8*)&xtb[((int)o4.x << 6) + c8];
            bf16x8 v01 = *(const bf16x8*)&xtb[((int)o4.y << 6) + c8];
            bf16x8 v10 = *(const bf16x8*)&xtb[((int)o4.z << 6) + c8];
            bf16x8 v11 = *(const bf16x8*)&xtb[((int)o4.w << 6) + c8];
            float w00 = (float)wb.x, w01 = (float)wb.y;
            float w10 = (float)wb.z, w11 = (float)wb.w;
            bf16x8 hv;
            #pragma unroll
            for (int j = 0; j < 8; ++j) {
                float r = w00 * (float)v00[j] + w01 * (float)v01[j]
                        + w10 * (float)v10[j] + w11 * (float)v11[j];
                hv[j] = (bf16)r;
            }
            int ks = 2 * kk + kpar;
            *(bf16x8*)(abw + (ks << 10)) = hv;      // byte (ks*64+flw)<<4
        };
        if (!khalf) {
            #pragma unroll
            for (int kk = 0; kk < 5; ++kk) gather1(kk);
        } else {
            #pragma unroll
            for (int kk = 5; kk < 9; ++kk) gather1(kk);
        }
        __syncthreads();

        // D: deform GEMM, wave = o-tile, hi-only
        f32x4 acc = {0.f, 0.f, 0.f, 0.f};
        __builtin_amdgcn_s_setprio(1);
        #pragma unroll
        for (int kk = 0; kk < 9; ++kk) {
            bf16x8 a0 = *(const bf16x8*)&a_s[(2 * kk) * 512 + fle];
            bf16x8 a1 = *(const bf16x8*)&a_s[(2 * kk + 1) * 512 + flo];
            acc = MFMA(a0, bhd[(2 * kk) * 64], acc);
            acc = MFMA(a1, bhd[(2 * kk + 1) * 64], acc);
        }
        __builtin_amdgcn_s_setprio(0);
        int o = wave * 16 + m;
        float bias = db[o];
        float4 vv = {acc[0] + bias, acc[1] + bias, acc[2] + bias, acc[3] + bias};
        *(float4*)&out[((size_t)(b * 64 + o)) * HW + ho * 128 + wo0 + st * 16 + g * 4] = vv;
        if (st < 1) __syncthreads();                // a_s reads done before overwrite
    }
}

extern "C" void kernel_launch(void* const* d_in, const int* in_sizes, int n_in,
                              void* d_out, int out_size, void* d_ws, size_t ws_size,
                              hipStream_t stream) {
    const float* x   = (const float*)d_in[0];
    const float* ow  = (const float*)d_in[1];
    const float* ob  = (const float*)d_in[2];
    const float* mw  = (const float*)d_in[3];
    const float* mb  = (const float*)d_in[4];
    const float* dw  = (const float*)d_in[5];
    const float* db  = (const float*)d_in[6];
    float* out = (float*)d_out;

    bf16* xt = (bf16*)d_ws;                         // 4,194,304 bf16 = 8 MB
    bf16* wfd_hi = xt + (size_t)BB * HW * CC;
    bf16* wfd_lo = wfd_hi + 36864;
    bf16* wfo_hi = wfd_lo + 36864;
    bf16* wfo_lo = wfo_hi + 18432;

    k_pre<<<1024 + 216, 256, 0, stream>>>(x, xt, dw, ow, mw, wfd_hi, wfd_lo, wfo_hi, wfo_lo);
    k_fused<<<(BB * HW) / 32, 256, 0, stream>>>(xt, wfo_hi, wfo_lo, wfd_hi, ob, mb, db, out);
}

// Round 8
// 120.103 us; speedup vs baseline: 1.0634x; 1.0634x over previous
//
#include <hip/hip_runtime.h>
#include <hip/hip_bf16.h>
#include <math.h>

// Problem constants
#define BB 4
#define CC 64
#define HH 128
#define WW 128
#define HW 16384
#define CHW (CC*HW)

typedef __bf16 bf16;
typedef __attribute__((ext_vector_type(8))) __bf16 bf16x8;
typedef __attribute__((ext_vector_type(4))) __bf16 bf16x4;
typedef __attribute__((ext_vector_type(4))) float f32x4;
typedef __attribute__((ext_vector_type(4))) unsigned short u16x4;

#define MFMA(a, b, c) __builtin_amdgcn_mfma_f32_16x16x32_bf16((a), (b), (c), 0, 0, 0)

// ---- Pre-kernel: x NCHW -> NHWC bf16 (blocks 0..2047) + weight frags ----
__global__ __launch_bounds__(256) void k_pre(const float* __restrict__ x,
        bf16* __restrict__ xt,
        const float* __restrict__ dw, const float* __restrict__ ow,
        const float* __restrict__ mw,
        bf16* __restrict__ wfd_hi, bf16* __restrict__ wfd_lo,
        bf16* __restrict__ wfo_hi, bf16* __restrict__ wfo_lo) {
    __shared__ float tile[64][33];
    if (blockIdx.x < 2048) {
        int b    = blockIdx.x >> 9;
        int s0   = (blockIdx.x & 511) * 32;
        int t    = threadIdx.x;
        const float* xb = x + (size_t)b * CHW;
        // float4 reads: 512 tasks = 64 rows x 8 col4-chunks
        #pragma unroll
        for (int it = 0; it < 2; ++it) {
            int task = it * 256 + t;
            int c    = task >> 3;
            int col4 = (task & 7) * 4;
            float4 v = *(const float4*)&xb[(size_t)c * HW + s0 + col4];
            tile[c][col4 + 0] = v.x;
            tile[c][col4 + 1] = v.y;
            tile[c][col4 + 2] = v.z;
            tile[c][col4 + 3] = v.w;
        }
        __syncthreads();
        bf16* xtb = xt + (size_t)b * CHW;
        // 256 tasks: 32 s x 8 ch-chunks -> 16B stores
        {
            int s = t >> 3, ch0 = (t & 7) * 8;
            bf16x8 v;
            #pragma unroll
            for (int j = 0; j < 8; ++j) v[j] = (bf16)tile[ch0 + j][s];
            *(bf16x8*)&xtb[(size_t)(s0 + s) * 64 + ch0] = v;
        }
    } else {
        int idx = (blockIdx.x - 2048) * 256 + threadIdx.x;
        if (idx < 36864) {                          // deform frags: 4 nt * 18 ks * 64 lanes * 8
            int j    = idx & 7;
            int lane = (idx >> 3) & 63;
            int ks   = (idx >> 9) % 18;
            int nt   = idx / (512 * 18);
            int n    = nt * 16 + (lane & 15);
            int kglob = ks * 32 + (lane >> 4) * 8 + j;
            int kk = kglob >> 6, c = kglob & 63;    // K-order: k = kk*64 + c
            float w = dw[(n * 64 + c) * 9 + kk];
            bf16 h = (bf16)w;
            wfd_hi[idx] = h;
            wfd_lo[idx] = (bf16)(w - (float)h);
        } else {
            int idx2 = idx - 36864;                 // offmask frags: 2 nt
            int j    = idx2 & 7;
            int lane = (idx2 >> 3) & 63;
            int ks   = (idx2 >> 9) % 18;
            int nt   = idx2 / (512 * 18);
            int ch   = nt * 16 + (lane & 15);
            int kglob = ks * 32 + (lane >> 4) * 8 + j;
            int kk = kglob >> 6, c = kglob & 63;
            float w = 0.0f;
            if (ch < 18)      w = ow[(ch * 64 + c) * 9 + kk];
            else if (ch < 27) w = mw[((ch - 18) * 64 + c) * 9 + kk];
            bf16 h = (bf16)w;
            wfo_hi[idx2] = h;
            wfo_lo[idx2] = (bf16)(w - (float)h);
        }
    }
}

// ---- Fused kernel (R4 geometry): 64 pos/block, paired-st C2 + merged D ----
// B : offset/mask GEMM, wave = st, A-frags direct from global -> om_s
// C1: 576 tasks precompute bilinear scalars -> sampw/sampo
// per st-PAIR sp:
//   C2: software-pipelined gather (samp 2-ahead, corners 1-ahead) -> a_s2
//   D : ONE merged loop, both half-sts: shared B-operand loads, dual acc chains
__global__ __launch_bounds__(256) void k_fused(const bf16* __restrict__ xt,
        const bf16* __restrict__ wfo_hi, const bf16* __restrict__ wfo_lo,
        const bf16* __restrict__ wfd_hi,
        const float* __restrict__ ob, const float* __restrict__ mb,
        const float* __restrict__ db, float* __restrict__ out) {
    __shared__ __align__(16) bf16 a_s2[2][18 * 64 * 8];    // 36864 B (st-pair)
    __shared__ float om_s[27 * 64];                        // 6912 B
    __shared__ __align__(8) bf16 sampw[576 * 4];           // 4608 B
    __shared__ __align__(8) unsigned short sampo[576 * 4]; // 4608 B

    // XCD-chunked swizzle (1024 blocks, 8 XCDs, bijective)
    int bid = (blockIdx.x & 7) * 128 + (blockIdx.x >> 3);
    int pos0 = bid * 64;
    int wo0 = pos0 & 127;
    int ho  = (pos0 >> 7) & 127;
    int b   = pos0 >> 14;
    int t = threadIdx.x, wave = t >> 6, lane = t & 63;
    int m = lane & 15, g = lane >> 4;
    const bf16* xtb = xt + (size_t)b * CHW;

    // ---- Phase B: offset/mask GEMM, wave = st, A-frags direct from global ----
    {
        int st = wave;
        f32x4 acc0 = {0.f, 0.f, 0.f, 0.f};
        f32x4 acc1 = {0.f, 0.f, 0.f, 0.f};
        const bf16x8* bh0 = (const bf16x8*)wfo_hi + lane;
        const bf16x8* bl0 = (const bf16x8*)wfo_lo + lane;
        const bf16x8* bh1 = (const bf16x8*)wfo_hi + 18 * 64 + lane;
        const bf16x8* bl1 = (const bf16x8*)wfo_lo + 18 * 64 + lane;
        #pragma unroll
        for (int kk = 0; kk < 9; ++kk) {
            int y  = ho + kk / 3 - 1;
            int xx = wo0 + st * 16 + m + (kk % 3) - 1;
            bf16x8 ae = {};
            bf16x8 ao = {};
            if ((unsigned)y < 128u && (unsigned)xx < 128u) {
                const bf16* bp = xtb + ((size_t)(y * 128 + xx) << 6);
                ae = *(const bf16x8*)(bp + g * 8);
                ao = *(const bf16x8*)(bp + 32 + g * 8);
            }
            int ks0 = 2 * kk, ks1 = 2 * kk + 1;
            acc0 = MFMA(ae, bh0[ks0 * 64], acc0);
            acc0 = MFMA(ae, bl0[ks0 * 64], acc0);
            acc0 = MFMA(ao, bh0[ks1 * 64], acc0);
            acc0 = MFMA(ao, bl0[ks1 * 64], acc0);
            acc1 = MFMA(ae, bh1[ks0 * 64], acc1);
            acc1 = MFMA(ae, bl1[ks0 * 64], acc1);
            acc1 = MFMA(ao, bh1[ks1 * 64], acc1);
            acc1 = MFMA(ao, bl1[ks1 * 64], acc1);
        }
        int p64 = st * 16 + g * 4;
        float bias0 = ob[m];                        // ch = m, always < 18
        #pragma unroll
        for (int r = 0; r < 4; ++r)
            om_s[m * 64 + p64 + r] = acc0[r] + bias0;
        int ch1 = 16 + m;
        if (ch1 < 27) {
            float bias1 = (ch1 < 18) ? ob[ch1] : mb[ch1 - 18];
            #pragma unroll
            for (int r = 0; r < 4; ++r) {
                float v = acc1[r] + bias1;
                if (ch1 >= 18) v = 1.0f / (1.0f + __expf(-v));
                om_s[ch1 * 64 + p64 + r] = v;
            }
        }
    }
    __syncthreads();

    // ---- Phase C1: bilinear scalar precompute (576 tasks) ----
    for (int task = t; task < 576; task += 256) {
        int p64 = task / 9, k = task - p64 * 9;
        float dy = om_s[(2 * k) * 64 + p64];
        float dx = om_s[(2 * k + 1) * 64 + p64];
        float mk = om_s[(18 + k) * 64 + p64];
        float py = (float)(ho - 1 + k / 3) + dy;
        float px = (float)(wo0 + p64 - 1 + (k % 3)) + dx;
        float y0f = floorf(py), x0f = floorf(px);
        float fy = py - y0f, fx = px - x0f;
        int y0 = (int)y0f, x0 = (int)x0f;
        int y1 = y0 + 1,  x1 = x0 + 1;
        bool vy0 = (unsigned)y0 < 128u, vy1 = (unsigned)y1 < 128u;
        bool vx0 = (unsigned)x0 < 128u, vx1 = (unsigned)x1 < 128u;
        int y0c = min(max(y0, 0), 127), y1c = min(max(y1, 0), 127);
        int x0c = min(max(x0, 0), 127), x1c = min(max(x1, 0), 127);
        bf16x4 wv;
        wv.x = (bf16)((vy0 && vx0) ? mk * (1.f - fy) * (1.f - fx) : 0.f);
        wv.y = (bf16)((vy0 && vx1) ? mk * (1.f - fy) * fx         : 0.f);
        wv.z = (bf16)((vy1 && vx0) ? mk * fy * (1.f - fx)         : 0.f);
        wv.w = (bf16)((vy1 && vx1) ? mk * fy * fx                 : 0.f);
        u16x4 ov;
        ov.x = (unsigned short)(y0c * 128 + x0c);
        ov.y = (unsigned short)(y0c * 128 + x1c);
        ov.z = (unsigned short)(y1c * 128 + x0c);
        ov.w = (unsigned short)(y1c * 128 + x1c);
        *(bf16x4*)&sampw[task * 4] = wv;
        *(u16x4*)&sampo[task * 4] = ov;
    }
    __syncthreads();

    // ---- st-pair loop: pipelined C2 gather -> merged D GEMM ----
    const bf16x8* bhd = (const bf16x8*)wfd_hi + (size_t)wave * 18 * 64 + lane;
    int fle = ((m ^ g) + (g << 4)) * 8;             // D-read offsets (elements)
    int flo = ((m ^ g ^ 4) + (g << 4)) * 8;
    // C2 thread mapping: half selects st within pair
    int half = t >> 7;
    int prow = (t >> 3) & 15;
    int c8   = (t & 7) * 8;
    int kpar = c8 >> 5;
    int gch  = (c8 & 31) >> 3;
    int flw  = (prow ^ gch ^ (kpar << 2)) + (gch << 4);   // write slot (16B units)
    char* abw = (char*)&a_s2[half][0] + (flw << 4);

    #pragma unroll
    for (int sp = 0; sp < 2; ++sp) {
        // ---- C2: software-pipelined gather into a_s2[half] ----
        {
            int stc = sp * 2 + half;
            int taskbase = (stc * 16 + prow) * 9;
            bf16x4 wbuf[2]; u16x4 obuf[2]; bf16x8 cbuf[2][4];
            auto ldsamp = [&](int kk) {
                int tk = taskbase + kk;
                wbuf[kk & 1] = *(const bf16x4*)&sampw[tk * 4];
                obuf[kk & 1] = *(const u16x4*)&sampo[tk * 4];
            };
            auto ldcor = [&](int kk) {
                u16x4 o = obuf[kk & 1];
                cbuf[kk & 1][0] = *(const bf16x8*)&xtb[((int)o.x << 6) + c8];
                cbuf[kk & 1][1] = *(const bf16x8*)&xtb[((int)o.y << 6) + c8];
                cbuf[kk & 1][2] = *(const bf16x8*)&xtb[((int)o.z << 6) + c8];
                cbuf[kk & 1][3] = *(const bf16x8*)&xtb[((int)o.w << 6) + c8];
            };
            auto docompute = [&](int kk) {
                bf16x4 wv = wbuf[kk & 1];
                float w00 = (float)wv.x, w01 = (float)wv.y;
                float w10 = (float)wv.z, w11 = (float)wv.w;
                bf16x8 hv;
                #pragma unroll
                for (int j = 0; j < 8; ++j) {
                    float r = w00 * (float)cbuf[kk & 1][0][j]
                            + w01 * (float)cbuf[kk & 1][1][j]
                            + w10 * (float)cbuf[kk & 1][2][j]
                            + w11 * (float)cbuf[kk & 1][3][j];
                    hv[j] = (bf16)r;
                }
                int ks = 2 * kk + kpar;
                *(bf16x8*)(abw + (ks << 10)) = hv;  // byte (ks*64+flw)<<4
            };
            ldsamp(0); ldcor(0); ldsamp(1);
            #pragma unroll
            for (int kk = 0; kk < 9; ++kk) {
                if (kk < 8) ldcor(kk + 1);          // issue next loads first
                docompute(kk);                      // then consume current
                if (kk < 7) ldsamp(kk + 2);         // samp 2 ahead
            }
        }
        __syncthreads();

        // ---- D: merged deform GEMM for both half-sts, wave = o-tile ----
        {
            f32x4 acc0 = {0.f, 0.f, 0.f, 0.f};
            f32x4 acc1 = {0.f, 0.f, 0.f, 0.f};
            #pragma unroll
            for (int kk = 0; kk < 9; ++kk) {
                bf16x8 b0 = bhd[(2 * kk) * 64];
                bf16x8 b1 = bhd[(2 * kk + 1) * 64];
                bf16x8 a0e = *(const bf16x8*)&a_s2[0][(2 * kk) * 512 + fle];
                bf16x8 a0o = *(const bf16x8*)&a_s2[0][(2 * kk + 1) * 512 + flo];
                bf16x8 a1e = *(const bf16x8*)&a_s2[1][(2 * kk) * 512 + fle];
                bf16x8 a1o = *(const bf16x8*)&a_s2[1][(2 * kk + 1) * 512 + flo];
                acc0 = MFMA(a0e, b0, acc0);
                acc1 = MFMA(a1e, b0, acc1);
                acc0 = MFMA(a0o, b1, acc0);
                acc1 = MFMA(a1o, b1, acc1);
            }
            int o = wave * 16 + m;
            float bias = db[o];
            int st0 = sp * 2;
            float4 v0 = {acc0[0] + bias, acc0[1] + bias, acc0[2] + bias, acc0[3] + bias};
            float4 v1 = {acc1[0] + bias, acc1[1] + bias, acc1[2] + bias, acc1[3] + bias};
            size_t obase = ((size_t)(b * 64 + o)) * HW + ho * 128 + wo0 + g * 4;
            *(float4*)&out[obase + st0 * 16] = v0;
            *(float4*)&out[obase + (st0 + 1) * 16] = v1;
        }
        if (sp == 0) __syncthreads();
    }
}

extern "C" void kernel_launch(void* const* d_in, const int* in_sizes, int n_in,
                              void* d_out, int out_size, void* d_ws, size_t ws_size,
                              hipStream_t stream) {
    const float* x   = (const float*)d_in[0];
    const float* ow  = (const float*)d_in[1];
    const float* ob  = (const float*)d_in[2];
    const float* mw  = (const float*)d_in[3];
    const float* mb  = (const float*)d_in[4];
    const float* dw  = (const float*)d_in[5];
    const float* db  = (const float*)d_in[6];
    float* out = (float*)d_out;

    bf16* xt = (bf16*)d_ws;                         // 4,194,304 bf16 = 8 MB
    bf16* wfd_hi = xt + (size_t)BB * HW * CC;
    bf16* wfd_lo = wfd_hi + 36864;
    bf16* wfo_hi = wfd_lo + 36864;
    bf16* wfo_lo = wfo_hi + 18432;

    k_pre<<<2048 + 216, 256, 0, stream>>>(x, xt, dw, ow, mw, wfd_hi, wfd_lo, wfo_hi, wfo_lo);
    k_fused<<<(BB * HW) / 64, 256, 0, stream>>>(xt, wfo_hi, wfo_lo, wfd_hi, ob, mb, db, out);
}